// Round 4
// baseline (48.180 us; speedup 1.0000x reference)
//
#include <hip/hip_runtime.h>

#define NS   48          // samples per ray
#define NSM1 47          // segments per ray
#define NC   32          // color channels
#define WPB  4           // waves (rays) per block -> 256 threads
#define MMB  64          // minmax pre-kernel blocks (== lanes in a wave!)

typedef float f4v __attribute__((ext_vector_type(4)));

// ---------- pre-pass: global depth min/max -> 64 float2 partials ----------
// depths are sorted along S, so per-ray min = s[0], max = s[47].
__launch_bounds__(512)
__global__ void depth_minmax_partials(const float* __restrict__ depths,
                                      float2* __restrict__ partials,
                                      int nrays) {
    const int tid  = threadIdx.x;
    const int lane = tid & 63;
    const int wv   = tid >> 6;
    float mn = __uint_as_float(0x7f800000u);
    float mx = -mn;
    for (int r = blockIdx.x * 512 + tid; r < nrays; r += MMB * 512) {
        mn = fminf(mn, depths[(size_t)r * NS]);
        mx = fmaxf(mx, depths[(size_t)r * NS + NSM1]);
    }
#pragma unroll
    for (int off = 32; off; off >>= 1) {
        mn = fminf(mn, __shfl_xor(mn, off));
        mx = fmaxf(mx, __shfl_xor(mx, off));
    }
    __shared__ float smn[8], smx[8];
    if (lane == 0) { smn[wv] = mn; smx[wv] = mx; }
    __syncthreads();
    if (tid == 0) {
#pragma unroll
        for (int w = 1; w < 8; ++w) {
            mn = fminf(smn[0] = fminf(smn[0], smn[w]), smn[0]);
            smx[0] = fmaxf(smx[0], smx[w]);
        }
        partials[blockIdx.x] = make_float2(smn[0], smx[0]);
    }
}

// ------------- main ray-march kernel: barrier-free, LDS-free ---------------
__launch_bounds__(WPB * 64)
__global__ void raymarch_kernel(const float* __restrict__ colors,
                                const float* __restrict__ densities,
                                const float* __restrict__ depths,
                                const float* __restrict__ sc,
                                const float2* __restrict__ partials,
                                float* __restrict__ out_rgb,
                                float* __restrict__ out_depth,
                                float* __restrict__ out_w,
                                float* __restrict__ out_xyz,
                                float* __restrict__ out_wt,
                                int nrays) {
    const int lane = threadIdx.x & 63;
    const int wv   = threadIdx.x >> 6;
    const int r    = blockIdx.x * WPB + wv;
    const bool active = (r < nrays);
    const int rr = active ? r : (nrays - 1);

    // ---- issue all long-latency loads FIRST ------------------------------
    const float2 pp = partials[lane];            // 64 entries == 64 lanes

    const f4v* colp = (const f4v*)(colors + (size_t)rr * (NS * NC));
    f4v cv[6];
#pragma unroll
    for (int t = 0; t < 6; ++t)
        cv[t] = __builtin_nontemporal_load(colp + t * 64 + lane);

    // sample-coordinate midpoint inputs, read directly (L1 absorbs overlap)
    const float* scp = sc + (size_t)rr * (NS * 3);
    const int b3 = (lane < NSM1) ? 3 * lane : 0;   // clamp keeps loads in-bounds
    const float s0 = scp[b3 + 0], s1 = scp[b3 + 1], s2 = scp[b3 + 2];
    const float s3 = scp[b3 + 3], s4 = scp[b3 + 4], s5 = scp[b3 + 5];

    const size_t rbase = (size_t)rr * NS;
    float d = 0.0f, de = 0.0f;
    if (lane < NS) {
        d  = depths[rbase + lane];
        de = densities[rbase + lane];
    }

    // ---- phase A: per-segment alpha / transmittance / weights -----------
    const float d1  = __shfl_down(d, 1);
    const float de1 = __shfl_down(de, 1);

    float alpha = 0.0f, dmid = 0.0f, f = 1.0f;
    if (lane < NSM1) {
        const float delta = d1 - d;
        dmid = 0.5f * (d + d1);
        const float x  = 0.5f * (de + de1) - 1.0f;
        const float sp = fmaxf(x, 0.0f) + __logf(1.0f + __expf(-fabsf(x)));
        alpha = 1.0f - __expf(-sp * delta);
        f = 1.0f - alpha + 1e-10f;
    }

    // exclusive prefix product of f -> transmittance
    float g = __shfl_up(f, 1);
    if (lane == 0) g = 1.0f;
#pragma unroll
    for (int off = 1; off < 64; off <<= 1) {
        const float v = __shfl_up(g, off);
        if (lane >= off) g *= v;
    }
    const float wgt = (lane < NSM1) ? alpha * g : 0.0f;

    // weight_total and depth numerator
    float wt = wgt, dsum = wgt * dmid;
#pragma unroll
    for (int off = 32; off; off >>= 1) {
        wt   += __shfl_xor(wt, off);
        dsum += __shfl_xor(dsum, off);
    }

    // ---- color coefficients entirely in-register --------------------------
    // a_full (lane j) = 0.5*(w[j-1] + w[j]); lane63 holds w=0 -> j=0 case free
    const float a_full = 0.5f * (wgt + __shfl(wgt, (lane - 1) & 63));

    const int soff = lane >> 3;
    f4v acc = {0.f, 0.f, 0.f, 0.f};
#pragma unroll
    for (int t = 0; t < 6; ++t) {
        const float a = __shfl(a_full, t * 8 + soff);
        acc += a * cv[t];
    }
#pragma unroll
    for (int off = 8; off < 64; off <<= 1) {
        acc.x += __shfl_xor(acc.x, off);
        acc.y += __shfl_xor(acc.y, off);
        acc.z += __shfl_xor(acc.z, off);
        acc.w += __shfl_xor(acc.w, off);
    }
    if (active && lane < 8) {
        f4v o;
        o.x = fmaf(acc.x, 2.0f, -1.0f);
        o.y = fmaf(acc.y, 2.0f, -1.0f);
        o.z = fmaf(acc.z, 2.0f, -1.0f);
        o.w = fmaf(acc.w, 2.0f, -1.0f);
        __builtin_nontemporal_store(o, (f4v*)out_rgb + (size_t)r * (NC / 4) + lane);
    }

    // ---- weights_out, xyz ------------------------------------------------
    float px = 0.f, py = 0.f, pz = 0.f;
    if (lane < NSM1) {
        const float wout = wgt + ((lane == NSM1 - 1) ? (1.0f - wt) : 0.0f);
        px = wout * (0.5f * (s0 + s3));
        py = wout * (0.5f * (s1 + s4));
        pz = wout * (0.5f * (s2 + s5));
        if (active)
            __builtin_nontemporal_store(wout, out_w + (size_t)r * NSM1 + lane);
    }
#pragma unroll
    for (int off = 32; off; off >>= 1) {
        px += __shfl_xor(px, off);
        py += __shfl_xor(py, off);
        pz += __shfl_xor(pz, off);
    }

    // ---- global depth minmax reduce (from hoisted partials) + tail write --
    float gmn = pp.x, gmx = pp.y;
#pragma unroll
    for (int off = 32; off; off >>= 1) {
        gmn = fminf(gmn, __shfl_xor(gmn, off));
        gmx = fmaxf(gmx, __shfl_xor(gmx, off));
    }
    if (active && lane == 0) {
        float cd = dsum / wt;
        if (!(cd == cd)) cd = gmx;                 // NaN -> inf -> clip to max
        cd = fminf(fmaxf(cd, gmn), gmx);
        out_depth[r] = cd;
        out_wt[r]    = wt;
        out_xyz[(size_t)r * 3 + 0] = px;
        out_xyz[(size_t)r * 3 + 1] = py;
        out_xyz[(size_t)r * 3 + 2] = pz;
    }
}

extern "C" void kernel_launch(void* const* d_in, const int* in_sizes, int n_in,
                              void* d_out, int out_size, void* d_ws, size_t ws_size,
                              hipStream_t stream) {
    const float* colors    = (const float*)d_in[0];
    const float* densities = (const float*)d_in[1];
    const float* depths    = (const float*)d_in[2];
    const float* sc        = (const float*)d_in[3];

    const int nrays   = in_sizes[1] / NS;   // densities is [B,R,S,1]
    const int nblocks = (nrays + WPB - 1) / WPB;

    float* out       = (float*)d_out;
    float* out_rgb   = out;                                   // [nrays, 32]
    float* out_depth = out_rgb + (size_t)nrays * NC;          // [nrays, 1]
    float* out_w     = out_depth + nrays;                     // [nrays, 47]
    float* out_xyz   = out_w + (size_t)nrays * NSM1;          // [nrays, 3]
    float* out_wt    = out_xyz + (size_t)nrays * 3;           // [nrays, 1]

    float2* partials = (float2*)d_ws;       // needs 64*8 = 512 B of ws

    hipLaunchKernelGGL(depth_minmax_partials, dim3(MMB), dim3(512), 0, stream,
                       depths, partials, nrays);
    hipLaunchKernelGGL(raymarch_kernel, dim3(nblocks), dim3(WPB * 64), 0, stream,
                       colors, densities, depths, sc, partials,
                       out_rgb, out_depth, out_w, out_xyz, out_wt, nrays);
}

// Round 5
// 41.179 us; speedup vs baseline: 1.1700x; 1.1700x over previous
//
#include <hip/hip_runtime.h>

#define NS   48          // samples per ray
#define NSM1 47          // segments per ray
#define NC   32          // color channels
#define WPB  4           // waves (rays) per block -> 256 threads

typedef float f4v __attribute__((ext_vector_type(4)));

// Single-kernel ray-march compositing. Barrier-free, LDS-free: each wave owns
// one ray. The reference's global-depth-range clip is a provable no-op for
// finite outputs (composite_depth is a convex combination of per-ray mid
// depths, which lie inside the per-ray [d0,d47] range, itself inside the
// global range) -- so we clamp to the per-ray range instead, which is equally
// a no-op but needs no global reduction / extra kernel.
__launch_bounds__(WPB * 64)
__global__ void raymarch_kernel(const float* __restrict__ colors,
                                const float* __restrict__ densities,
                                const float* __restrict__ depths,
                                const float* __restrict__ sc,
                                float* __restrict__ out_rgb,
                                float* __restrict__ out_depth,
                                float* __restrict__ out_w,
                                float* __restrict__ out_xyz,
                                float* __restrict__ out_wt,
                                int nrays) {
    const int lane = threadIdx.x & 63;
    const int wv   = threadIdx.x >> 6;
    const int r    = blockIdx.x * WPB + wv;
    const bool active = (r < nrays);
    const int rr = active ? r : (nrays - 1);

    // ---- issue all long-latency loads FIRST ------------------------------
    const f4v* colp = (const f4v*)(colors + (size_t)rr * (NS * NC));
    f4v cv[6];
#pragma unroll
    for (int t = 0; t < 6; ++t) cv[t] = colp[t * 64 + lane];

    // sample-coordinate midpoint inputs (overlapping reads, L1-served)
    const float* scp = sc + (size_t)rr * (NS * 3);
    const int b3 = (lane < NSM1) ? 3 * lane : 0;   // clamp keeps loads in-bounds
    const float s0 = scp[b3 + 0], s1 = scp[b3 + 1], s2 = scp[b3 + 2];
    const float s3 = scp[b3 + 3], s4 = scp[b3 + 4], s5 = scp[b3 + 5];

    const size_t rbase = (size_t)rr * NS;
    float d = 0.0f, de = 0.0f;
    if (lane < NS) {
        d  = depths[rbase + lane];
        de = densities[rbase + lane];
    }

    // ---- phase A: per-segment alpha / transmittance / weights -----------
    const float d1  = __shfl_down(d, 1);
    const float de1 = __shfl_down(de, 1);
    const float gmn = __shfl(d, 0);       // per-ray depth min (sorted)
    const float gmx = __shfl(d, NSM1);    // per-ray depth max

    float alpha = 0.0f, dmid = 0.0f, f = 1.0f;
    if (lane < NSM1) {
        const float delta = d1 - d;
        dmid = 0.5f * (d + d1);
        const float x  = 0.5f * (de + de1) - 1.0f;
        const float sp = fmaxf(x, 0.0f) + __logf(1.0f + __expf(-fabsf(x)));
        alpha = 1.0f - __expf(-sp * delta);
        f = 1.0f - alpha + 1e-10f;
    }

    // exclusive prefix product of f -> transmittance
    float g = __shfl_up(f, 1);
    if (lane == 0) g = 1.0f;
#pragma unroll
    for (int off = 1; off < 64; off <<= 1) {
        const float v = __shfl_up(g, off);
        if (lane >= off) g *= v;
    }
    const float wgt = (lane < NSM1) ? alpha * g : 0.0f;

    // weight_total and depth numerator
    float wt = wgt, dsum = wgt * dmid;
#pragma unroll
    for (int off = 32; off; off >>= 1) {
        wt   += __shfl_xor(wt, off);
        dsum += __shfl_xor(dsum, off);
    }

    // ---- color coefficients entirely in-register --------------------------
    // a_full (lane j) = 0.5*(w[j-1] + w[j]); lane63 holds w=0 -> j=0 case free
    const float a_full = 0.5f * (wgt + __shfl(wgt, (lane - 1) & 63));

    const int soff = lane >> 3;
    f4v acc = {0.f, 0.f, 0.f, 0.f};
#pragma unroll
    for (int t = 0; t < 6; ++t) {
        const float a = __shfl(a_full, t * 8 + soff);
        acc += a * cv[t];
    }
#pragma unroll
    for (int off = 8; off < 64; off <<= 1) {
        acc.x += __shfl_xor(acc.x, off);
        acc.y += __shfl_xor(acc.y, off);
        acc.z += __shfl_xor(acc.z, off);
        acc.w += __shfl_xor(acc.w, off);
    }
    if (active && lane < 8) {
        f4v o;
        o.x = fmaf(acc.x, 2.0f, -1.0f);
        o.y = fmaf(acc.y, 2.0f, -1.0f);
        o.z = fmaf(acc.z, 2.0f, -1.0f);
        o.w = fmaf(acc.w, 2.0f, -1.0f);
        ((f4v*)out_rgb)[(size_t)r * (NC / 4) + lane] = o;
    }

    // ---- weights_out, xyz ------------------------------------------------
    float px = 0.f, py = 0.f, pz = 0.f;
    if (lane < NSM1) {
        const float wout = wgt + ((lane == NSM1 - 1) ? (1.0f - wt) : 0.0f);
        px = wout * (0.5f * (s0 + s3));
        py = wout * (0.5f * (s1 + s4));
        pz = wout * (0.5f * (s2 + s5));
        if (active) out_w[(size_t)r * NSM1 + lane] = wout;
    }
#pragma unroll
    for (int off = 32; off; off >>= 1) {
        px += __shfl_xor(px, off);
        py += __shfl_xor(py, off);
        pz += __shfl_xor(pz, off);
    }

    if (active && lane == 0) {
        float cd = dsum / wt;
        if (!(cd == cd)) cd = gmx;        // NaN -> inf -> clip to max
        cd = fminf(fmaxf(cd, gmn), gmx);  // no-op clamp (safety)
        out_depth[r] = cd;
        out_wt[r]    = wt;
        out_xyz[(size_t)r * 3 + 0] = px;
        out_xyz[(size_t)r * 3 + 1] = py;
        out_xyz[(size_t)r * 3 + 2] = pz;
    }
}

extern "C" void kernel_launch(void* const* d_in, const int* in_sizes, int n_in,
                              void* d_out, int out_size, void* d_ws, size_t ws_size,
                              hipStream_t stream) {
    const float* colors    = (const float*)d_in[0];
    const float* densities = (const float*)d_in[1];
    const float* depths    = (const float*)d_in[2];
    const float* sc        = (const float*)d_in[3];

    const int nrays   = in_sizes[1] / NS;   // densities is [B,R,S,1]
    const int nblocks = (nrays + WPB - 1) / WPB;

    float* out       = (float*)d_out;
    float* out_rgb   = out;                                   // [nrays, 32]
    float* out_depth = out_rgb + (size_t)nrays * NC;          // [nrays, 1]
    float* out_w     = out_depth + nrays;                     // [nrays, 47]
    float* out_xyz   = out_w + (size_t)nrays * NSM1;          // [nrays, 3]
    float* out_wt    = out_xyz + (size_t)nrays * 3;           // [nrays, 1]

    hipLaunchKernelGGL(raymarch_kernel, dim3(nblocks), dim3(WPB * 64), 0, stream,
                       colors, densities, depths, sc,
                       out_rgb, out_depth, out_w, out_xyz, out_wt, nrays);
}